// Round 13
// baseline (595.567 us; speedup 1.0000x reference)
//
#include <hip/hip_runtime.h>
#include <math.h>

#define B_  32
#define W_  32
#define M_  1024
#define HD_ 64
#define RD_ 32
#define D_  128
#define CH_ 16           // time-steps per chunk (2 chunks)
#define NKT 16           // K-tiles (K=1024, BK=64) in gemm

typedef short bf16x8 __attribute__((ext_vector_type(8)));
typedef float f32x4  __attribute__((ext_vector_type(4)));

#define AS1 __attribute__((address_space(1)))
#define AS3 __attribute__((address_space(3)))

__device__ __forceinline__ void gload16(const void* g, void* l) {
    __builtin_amdgcn_global_load_lds((const AS1 void*)g, (AS3 void*)l, 16, 0, 0);
}

__device__ __forceinline__ unsigned short f2b(float f) {
    unsigned int u = __float_as_uint(f);
    u += 0x7fffu + ((u >> 16) & 1u);
    return (unsigned short)(u >> 16);
}
__device__ __forceinline__ float b2f(unsigned short h) {
    return __uint_as_float(((unsigned int)h) << 16);
}
__device__ __forceinline__ float sigf(float x) { return 1.0f / (1.0f + __expf(-x)); }
__device__ __forceinline__ float tanhf_(float x) { return 2.0f / (1.0f + __expf(-2.0f * x)) - 1.0f; }

// ---------------- setup kernels ----------------

__global__ __launch_bounds__(256) void gt_kernel(const float* __restrict__ G,
                                                 unsigned short* __restrict__ GTb) {
    __shared__ float T[64][65];
    int i0 = blockIdx.x * 64, j0 = blockIdx.y * 64;
    int tid = threadIdx.x;
    int r = tid >> 4, c4 = (tid & 15) * 4;
    #pragma unroll
    for (int q = 0; q < 4; ++q) {
        float4 v = *(const float4*)&G[(i0 + r + q * 16) * M_ + j0 + c4];
        T[r + q * 16][c4] = v.x; T[r + q * 16][c4 + 1] = v.y;
        T[r + q * 16][c4 + 2] = v.z; T[r + q * 16][c4 + 3] = v.w;
    }
    __syncthreads();
    #pragma unroll
    for (int q = 0; q < 4; ++q) {
        int jr = r + q * 16;
        ushort4 o;
        o.x = f2b(T[c4][jr]); o.y = f2b(T[c4 + 1][jr]);
        o.z = f2b(T[c4 + 2][jr]); o.w = f2b(T[c4 + 3][jr]);
        *(ushort4*)&GTb[(j0 + jr) * M_ + i0 + c4] = o;
    }
}

__global__ __launch_bounds__(192) void gh1ct_kernel(const float* __restrict__ H_init,
                                                    const float* __restrict__ Whh1,
                                                    const float* __restrict__ bhh1,
                                                    float* __restrict__ gh1cT) {
    int m = blockIdx.x, k = threadIdx.x;
    __shared__ float h01[HD_];
    if (k < HD_) h01[k] = H_init[(M_ + m) * HD_ + k];
    __syncthreads();
    float d = 0.f;
    #pragma unroll
    for (int hd = 0; hd < HD_; ++hd) d = fmaf(h01[hd], Whh1[k * HD_ + hd], d);
    gh1cT[k * M_ + m] = d + bhh1[k];
}

__global__ __launch_bounds__(128) void wn_kernel(const float* __restrict__ V,
                                                 const float* __restrict__ g,
                                                 unsigned short* __restrict__ Wnb) {
    int r = blockIdx.x, d = threadIdx.x;
    float v = V[r * D_ + d];
    float s = v * v;
    #pragma unroll
    for (int off = 32; off > 0; off >>= 1) s += __shfl_down(s, off);
    __shared__ float ws[2];
    if ((threadIdx.x & 63) == 0) ws[threadIdx.x >> 6] = s;
    __syncthreads();
    float norm = sqrtf(ws[0] + ws[1]);
    Wnb[r * D_ + d] = f2b(g[r] * v / norm);
}

__global__ __launch_bounds__(256) void castw_kernel(const float* __restrict__ Whh0,
                                                    const float* __restrict__ Wih1,
                                                    unsigned short* __restrict__ Whh0b,
                                                    unsigned short* __restrict__ Wih1b) {
    int i = blockIdx.x * 256 + threadIdx.x;  // < 12288
    Whh0b[i] = f2b(Whh0[i]);
    Wih1b[i] = f2b(Wih1[i]);
}

__global__ __launch_bounds__(256) void inith_kernel(const float* __restrict__ H_init,
                                                    unsigned short* __restrict__ Hb) {
    int e8 = blockIdx.x * 256 + threadIdx.x;   // 262144 total
    int base = e8 * 8;
    int src = base & (M_ * HD_ - 1);
    float4 v0 = *(const float4*)&H_init[src];
    float4 v1 = *(const float4*)&H_init[src + 4];
    uint4 u;
    u.x = (unsigned int)f2b(v0.x) | ((unsigned int)f2b(v0.y) << 16);
    u.y = (unsigned int)f2b(v0.z) | ((unsigned int)f2b(v0.w) << 16);
    u.z = (unsigned int)f2b(v1.x) | ((unsigned int)f2b(v1.y) << 16);
    u.w = (unsigned int)f2b(v1.z) | ((unsigned int)f2b(v1.w) << 16);
    *(uint4*)&Hb[base] = u;
}

// ---------------- per-chunk: fused GRU0+GRU1, 16 time-steps -----------------
// R7/R12-validated: byte-identical. 512 thr (8 waves), j-split, 3 barriers/step.
__global__ __launch_bounds__(512, 4) void gru_chunk_kernel(
    const float* __restrict__ x_input, const float* __restrict__ Wih0,
    const float* __restrict__ bih0, const float* __restrict__ bhh0,
    const unsigned short* __restrict__ Whh0b, const unsigned short* __restrict__ Wih1b,
    const float* __restrict__ bih1, const float* __restrict__ gh1cT,
    const float* __restrict__ H_init, unsigned short* __restrict__ Hb,
    unsigned short* __restrict__ XPT_c, int t0)
{
    __shared__ unsigned short Whh0s[192 * 64];   // 24 KB, swizzled rows of 8x16B
    __shared__ unsigned short Wih1s[192 * 64];   // 24 KB
    __shared__ unsigned short hn0s[64 * 64];     // 8 KB, swizzled
    __shared__ unsigned short hn1s[64 * 64];     // 8 KB, swizzled (current state)
    const int tid = threadIdx.x, w = tid >> 6, l = tid & 63;
    const int li = l & 15, lh = l >> 4;
    const int pg = w >> 1, hf = w & 1;           // pair-group / j-half
    const int b = blockIdx.x >> 4, mt = blockIdx.x & 15;
    const int m0 = mt * 64;
    const int p0b = b * M_ + m0;
    const int ms = m0 + pg * 16;

    for (int i = tid; i < 1536; i += 512) {
        int row = i >> 3, pos = i & 7, sc = pos ^ (row & 7);
        gload16(&Whh0b[row * 64 + sc * 8], (char*)Whh0s + (i & ~63) * 16);
        gload16(&Wih1b[row * 64 + sc * 8], (char*)Wih1s + (i & ~63) * 16);
    }
    {
        int p = tid >> 3, cc = tid & 7;
        uint4 v = *(const uint4*)&Hb[(p0b + p) * HD_ + cc * 8];
        *(uint4*)((char*)hn1s + p * 128 + ((cc ^ (p & 7)) << 4)) = v;
    }

    float wi_[3][2], bi0_[3][2], bh0_[3][2], bi1_[3][2];
    float vrA[2][4], vzA[2][4], vnA[2][4], h01A[2][4];
    #pragma unroll
    for (int fi = 0; fi < 2; ++fi) {
        int ko = hf * 32 + fi * 16 + li;
        #pragma unroll
        for (int g3 = 0; g3 < 3; ++g3) {
            wi_[g3][fi]  = Wih0[g3 * 64 + ko];
            bi0_[g3][fi] = bih0[g3 * 64 + ko];
            bh0_[g3][fi] = bhh0[g3 * 64 + ko];
            bi1_[g3][fi] = bih1[g3 * 64 + ko];
        }
        float4 vr = *(const float4*)&gh1cT[(ko) * M_ + ms + lh * 4];
        float4 vz = *(const float4*)&gh1cT[(64 + ko) * M_ + ms + lh * 4];
        float4 vn = *(const float4*)&gh1cT[(128 + ko) * M_ + ms + lh * 4];
        vrA[fi][0] = vr.x; vrA[fi][1] = vr.y; vrA[fi][2] = vr.z; vrA[fi][3] = vr.w;
        vzA[fi][0] = vz.x; vzA[fi][1] = vz.y; vzA[fi][2] = vz.z; vzA[fi][3] = vz.w;
        vnA[fi][0] = vn.x; vnA[fi][1] = vn.y; vnA[fi][2] = vn.z; vnA[fi][3] = vn.w;
        #pragma unroll
        for (int reg = 0; reg < 4; ++reg)
            h01A[fi][reg] = H_init[M_ * HD_ + (ms + lh * 4 + reg) * HD_ + ko];
    }

    __syncthreads();    // weights (gload drained) + hn1s visible

    float hst[2][4];
    #pragma unroll
    for (int fi = 0; fi < 2; ++fi) {
        int ko = hf * 32 + fi * 16 + li;
        #pragma unroll
        for (int reg = 0; reg < 4; ++reg) {
            int ml = pg * 16 + lh * 4 + reg;
            hst[fi][reg] = b2f(*(const unsigned short*)((char*)hn1s + ml * 128 +
                               ((((ko >> 3) ^ (ml & 7))) << 4) + (ko & 7) * 2));
        }
    }

    for (int ts = 0; ts < CH_; ++ts) {
        int t = t0 + ts;
        float4 xv = *(const float4*)&x_input[(b * W_ + t) * M_ + ms + lh * 4];
        float x4[4] = {xv.x, xv.y, xv.z, xv.w};
        const int rl = pg * 16 + li;

        // ---- GRU0 matvec (half): gh0[j in hf-range] = h(16x64) @ Whh0^T ----
        bf16x8 a0 = *(const bf16x8*)((char*)hn1s + rl * 128 + ((lh ^ (rl & 7)) << 4));
        bf16x8 a1 = *(const bf16x8*)((char*)hn1s + rl * 128 + (((4 + lh) ^ (rl & 7)) << 4));
        f32x4 acc[6];
        #pragma unroll
        for (int q = 0; q < 6; ++q) acc[q] = (f32x4){0.f, 0.f, 0.f, 0.f};
        #pragma unroll
        for (int g3 = 0; g3 < 3; ++g3)
            #pragma unroll
            for (int fi = 0; fi < 2; ++fi) {
                int row = (g3 * 4 + hf * 2 + fi) * 16 + li;
                bf16x8 b0 = *(const bf16x8*)((char*)Whh0s + row * 128 + ((lh ^ (row & 7)) << 4));
                bf16x8 b1 = *(const bf16x8*)((char*)Whh0s + row * 128 + (((4 + lh) ^ (row & 7)) << 4));
                acc[g3 * 2 + fi] = __builtin_amdgcn_mfma_f32_16x16x32_bf16(a0, b0, acc[g3 * 2 + fi], 0, 0, 0);
                acc[g3 * 2 + fi] = __builtin_amdgcn_mfma_f32_16x16x32_bf16(a1, b1, acc[g3 * 2 + fi], 0, 0, 0);
            }
        #pragma unroll
        for (int fi = 0; fi < 2; ++fi) {
            int j = hf * 32 + fi * 16 + li;
            #pragma unroll
            for (int reg = 0; reg < 4; ++reg) {
                int ml = pg * 16 + lh * 4 + reg;
                float x = x4[reg];
                float r = sigf(x * wi_[0][fi] + bi0_[0][fi] + acc[fi][reg]     + bh0_[0][fi]);
                float z = sigf(x * wi_[1][fi] + bi0_[1][fi] + acc[2 + fi][reg] + bh0_[1][fi]);
                float n = tanhf_(x * wi_[2][fi] + bi0_[2][fi] + r * (acc[4 + fi][reg] + bh0_[2][fi]));
                float h0v = (1.f - z) * n + z * hst[fi][reg];
                *(unsigned short*)((char*)hn0s + ml * 128 +
                    ((((j >> 3) ^ (ml & 7))) << 4) + (j & 7) * 2) = f2b(h0v);
            }
        }
        __syncthreads();   // both halves of hn0s ready

        // ---- GRU1 matvec (half): gi1[j in hf-range] = hn0(16x64) @ Wih1^T ----
        a0 = *(const bf16x8*)((char*)hn0s + rl * 128 + ((lh ^ (rl & 7)) << 4));
        a1 = *(const bf16x8*)((char*)hn0s + rl * 128 + (((4 + lh) ^ (rl & 7)) << 4));
        #pragma unroll
        for (int q = 0; q < 6; ++q) acc[q] = (f32x4){0.f, 0.f, 0.f, 0.f};
        #pragma unroll
        for (int g3 = 0; g3 < 3; ++g3)
            #pragma unroll
            for (int fi = 0; fi < 2; ++fi) {
                int row = (g3 * 4 + hf * 2 + fi) * 16 + li;
                bf16x8 b0 = *(const bf16x8*)((char*)Wih1s + row * 128 + ((lh ^ (row & 7)) << 4));
                bf16x8 b1 = *(const bf16x8*)((char*)Wih1s + row * 128 + (((4 + lh) ^ (row & 7)) << 4));
                acc[g3 * 2 + fi] = __builtin_amdgcn_mfma_f32_16x16x32_bf16(a0, b0, acc[g3 * 2 + fi], 0, 0, 0);
                acc[g3 * 2 + fi] = __builtin_amdgcn_mfma_f32_16x16x32_bf16(a1, b1, acc[g3 * 2 + fi], 0, 0, 0);
            }
        #pragma unroll
        for (int fi = 0; fi < 2; ++fi) {
            int ko = hf * 32 + fi * 16 + li;
            #pragma unroll
            for (int reg = 0; reg < 4; ++reg) {
                int ml = pg * 16 + lh * 4 + reg;
                float r = sigf(acc[fi][reg]     + bi1_[0][fi] + vrA[fi][reg]);
                float z = sigf(acc[2 + fi][reg] + bi1_[1][fi] + vzA[fi][reg]);
                float n = tanhf_(acc[4 + fi][reg] + bi1_[2][fi] + r * vnA[fi][reg]);
                float h1v = (1.f - z) * n + z * h01A[fi][reg];
                hst[fi][reg] = h1v;          // f32 recurrent carry
                *(unsigned short*)((char*)hn1s + ml * 128 +
                    ((((ko >> 3) ^ (ml & 7))) << 4) + (ko & 7) * 2) = f2b(h1v);
            }
        }
        __syncthreads();   // hn1s (new state) ready

        // ---- XPT write (transposed bf16 rows [c][m]); 512 thr pack 128 d ----
        {
            unsigned short* XPT = XPT_c + (size_t)ts * (D_ * B_ * M_);
            int d = tid >> 2, mh = (tid & 3) * 16;
            const char* src = (d < 64) ? (const char*)hn0s : (const char*)hn1s;
            int dd = d & 63;
            unsigned int pk[8];
            #pragma unroll
            for (int mm = 0; mm < 16; mm += 2) {
                int ma = mh + mm, mb = mh + mm + 1;
                unsigned int ua = *(const unsigned short*)(src + ma * 128 + (((dd >> 3) ^ (ma & 7)) << 4) + (dd & 7) * 2);
                unsigned int ub = *(const unsigned short*)(src + mb * 128 + (((dd >> 3) ^ (mb & 7)) << 4) + (dd & 7) * 2);
                pk[mm >> 1] = ua | (ub << 16);
            }
            uint4 o0 = {pk[0], pk[1], pk[2], pk[3]};
            uint4 o1 = {pk[4], pk[5], pk[6], pk[7]};
            *(uint4*)&XPT[(b * D_ + d) * M_ + m0 + mh]     = o0;
            *(uint4*)&XPT[(b * D_ + d) * M_ + m0 + mh + 8] = o1;
        }
        __syncthreads();   // pack reads done before next step's hn writes
    }

    // state writeback
    {
        int p = tid >> 3, cc = tid & 7;
        uint4 v = *(const uint4*)((char*)hn1s + p * 128 + ((cc ^ (p & 7)) << 4));
        *(uint4*)&Hb[(p0b + p) * HD_ + cc * 8] = v;
    }
}

// ---------------- per-chunk: 128x128 BK=64 dbuf graph GEMM + fused head -----
// R7 sync skeleton, geometry change only: 256 thr / 4 waves (2M x 2N),
// per-wave 64x64 output (acc 4x4). Halves ds_read_b128 per FLOP (the
// measured LDS-read-throughput bottleneck: 96 reads/block-kt -> 64).
// STAGE issues 8 loads/thread -> vmcnt(8). Grid mapping unchanged (4096).
__global__ __launch_bounds__(256, 2) void gemmhead_kernel(
    const unsigned short* __restrict__ GTb, const unsigned short* __restrict__ XPT_c,
    const unsigned short* __restrict__ Wnb, const float* __restrict__ b_lin,
    const float* __restrict__ W_fr, const float* __restrict__ b_fr,
    float* __restrict__ out, int t0)
{
    __shared__ __align__(16) char lds[65536];  // 2 x (A 16K + B 16K); reused as XGs 32K
    const int tid = threadIdx.x, w = tid >> 6, l = tid & 63;
    const int li = l & 15, lh = l >> 4;      // lh 0..3
    const int wm = w >> 1, wn = w & 1;       // 2 x 2 wave grid
    const int bid = blockIdx.x;
    const int ntile = (bid & 7) + ((bid >> 6) << 3);   // 0..511 (ts*32+b)
    const int j0 = ((bid >> 3) & 7) * 128;             // 8 j-tiles (same-XCD sharers)
    const unsigned short* Asrc = GTb + (size_t)j0 * M_;
    const unsigned short* Bsrc = XPT_c + (size_t)ntile * 128 * M_;

    f32x4 acc[4][4];
    #pragma unroll
    for (int mi = 0; mi < 4; ++mi)
        #pragma unroll
        for (int ni = 0; ni < 4; ++ni) acc[mi][ni] = (f32x4){0.f, 0.f, 0.f, 0.f};

    // stage A(128x64) + B(128x64) bf16: 1024 chunks each, 4/thread each.
    // source pre-swizzled pos^(row&7) -> linear LDS dest = swizzled layout
    #define STAGE(kt, c) { \
        _Pragma("unroll") \
        for (int q = 0; q < 4; ++q) { \
            int i = q * 256 + tid; \
            int row = i >> 3, pos = i & 7, sc = pos ^ (row & 7); \
            gload16(&Asrc[row * M_ + (kt) * 64 + sc * 8], lds + (c) * 32768 + (i & ~63) * 16); \
            gload16(&Bsrc[row * M_ + (kt) * 64 + sc * 8], lds + (c) * 32768 + 16384 + (i & ~63) * 16); \
        } }

    STAGE(0, 0);

    for (int kt = 0; kt < NKT; ++kt) {
        if (kt + 1 < NKT) { STAGE(kt + 1, (kt + 1) & 1);
                            asm volatile("s_waitcnt vmcnt(8)" ::: "memory"); }
        else              { asm volatile("s_waitcnt vmcnt(0)" ::: "memory"); }
        __builtin_amdgcn_s_barrier();
        asm volatile("" ::: "memory");
        const char* Abuf = lds + (kt & 1) * 32768;
        const char* Bbuf = Abuf + 16384;
        bf16x8 af[4][2], bfv[4][2];
        #pragma unroll
        for (int mi = 0; mi < 4; ++mi) {
            int row = wm * 64 + mi * 16 + li;
            #pragma unroll
            for (int kk = 0; kk < 2; ++kk)
                af[mi][kk] = *(const bf16x8*)(Abuf + row * 128 + (((kk * 4 + lh) ^ (row & 7)) << 4));
        }
        #pragma unroll
        for (int ni = 0; ni < 4; ++ni) {
            int row = wn * 64 + ni * 16 + li;
            #pragma unroll
            for (int kk = 0; kk < 2; ++kk)
                bfv[ni][kk] = *(const bf16x8*)(Bbuf + row * 128 + (((kk * 4 + lh) ^ (row & 7)) << 4));
        }
        __builtin_amdgcn_s_setprio(1);
        #pragma unroll
        for (int kk = 0; kk < 2; ++kk)
            #pragma unroll
            for (int mi = 0; mi < 4; ++mi)
                #pragma unroll
                for (int ni = 0; ni < 4; ++ni)
                    acc[mi][ni] = __builtin_amdgcn_mfma_f32_16x16x32_bf16(af[mi][kk], bfv[ni][kk], acc[mi][ni], 0, 0, 0);
        __builtin_amdgcn_s_setprio(0);
        asm volatile("s_waitcnt lgkmcnt(0)" ::: "memory");  // reads done before bar2
        __builtin_amdgcn_s_barrier();
        asm volatile("" ::: "memory");
    }

    __syncthreads();   // full drain; staging LDS becomes XGs

    // relu -> bf16 -> XGs[128][128] (row 256 B = 16 chunks, XOR low3 w/ row&7)
    #pragma unroll
    for (int mi = 0; mi < 4; ++mi)
        #pragma unroll
        for (int ni = 0; ni < 4; ++ni)
            #pragma unroll
            for (int reg = 0; reg < 4; ++reg) {
                int jl = wm * 64 + mi * 16 + lh * 4 + reg;
                int cl = wn * 64 + ni * 16 + li;
                float v = fmaxf(acc[mi][ni][reg], 0.f);
                int byte = jl * 256 + ((((cl >> 3) ^ (jl & 7))) << 4) + (cl & 7) * 2;
                *(unsigned short*)(lds + byte) = f2b(v);
            }
    __syncthreads();

    // head: wave w does rows w*32 .. w*32+31 (2 groups of 16)
    const int b = ntile & 31, t = t0 + (ntile >> 5);
    float bl0 = b_lin[li], bl1 = b_lin[16 + li];
    #pragma unroll
    for (int rg = 0; rg < 2; ++rg) {
        int row = w * 32 + rg * 16 + li;
        f32x4 P0 = (f32x4){0.f, 0.f, 0.f, 0.f};
        f32x4 P1 = (f32x4){0.f, 0.f, 0.f, 0.f};
        #pragma unroll
        for (int ks = 0; ks < 4; ++ks) {
            int cp = (ks * 4 + lh) ^ (row & 7);
            bf16x8 xa = *(const bf16x8*)(lds + row * 256 + cp * 16);
            bf16x8 wb0 = *(const bf16x8*)&Wnb[(li) * D_ + ks * 32 + lh * 8];
            bf16x8 wb1 = *(const bf16x8*)&Wnb[(16 + li) * D_ + ks * 32 + lh * 8];
            P0 = __builtin_amdgcn_mfma_f32_16x16x32_bf16(xa, wb0, P0, 0, 0, 0);
            P1 = __builtin_amdgcn_mfma_f32_16x16x32_bf16(xa, wb1, P1, 0, 0, 0);
        }
        float s[4];
        #pragma unroll
        for (int reg = 0; reg < 4; ++reg) {
            int j = j0 + w * 32 + rg * 16 + lh * 4 + reg;
            float y0 = sigf(P0[reg] + bl0);
            float y1 = sigf(P1[reg] + bl1);
            s[reg] = y0 * W_fr[j * RD_ + li] + y1 * W_fr[j * RD_ + 16 + li];
        }
        #pragma unroll
        for (int off = 1; off < 16; off <<= 1) {
            #pragma unroll
            for (int reg = 0; reg < 4; ++reg) s[reg] += __shfl_xor(s[reg], off);
        }
        if (li == 0) {
            int jb = j0 + w * 32 + rg * 16 + lh * 4;
            float4 o = {s[0] + b_fr[jb], s[1] + b_fr[jb + 1],
                        s[2] + b_fr[jb + 2], s[3] + b_fr[jb + 3]};
            *(float4*)&out[(b * W_ + t) * M_ + jb] = o;
        }
    }
}

// ---------------- launcher ----------------

extern "C" void kernel_launch(void* const* d_in, const int* in_sizes, int n_in,
                              void* d_out, int out_size, void* d_ws, size_t ws_size,
                              hipStream_t stream) {
    const float* x_input = (const float*)d_in[0];
    const float* G       = (const float*)d_in[1];
    const float* H_init  = (const float*)d_in[2];
    const float* Wih0    = (const float*)d_in[3];
    const float* Whh0    = (const float*)d_in[4];
    const float* bih0    = (const float*)d_in[5];
    const float* bhh0    = (const float*)d_in[6];
    const float* Wih1    = (const float*)d_in[7];
    const float* Whh1    = (const float*)d_in[8];
    const float* bih1    = (const float*)d_in[9];
    const float* bhh1    = (const float*)d_in[10];
    const float* V       = (const float*)d_in[11];
    const float* gvec    = (const float*)d_in[12];
    const float* b_lin   = (const float*)d_in[13];
    const float* W_fr    = (const float*)d_in[14];
    const float* b_fr    = (const float*)d_in[15];
    float* out = (float*)d_out;

    // ws layout (bytes), total ~135.1 MiB of the 256 MiB workspace
    char* ws = (char*)d_ws;
    unsigned short* GTb   = (unsigned short*)(ws);                   //   2 MiB
    unsigned short* XPT_c = (unsigned short*)(ws + (2u   << 20));    // 128 MiB (16 steps x 8 MiB)
    unsigned short* Hb    = (unsigned short*)(ws + (130u << 20));    //   4 MiB
    float*          gh1cT = (float*)(ws + (134u << 20));             // 768 KiB
    unsigned short* Wnb   = (unsigned short*)(ws + (135u << 20));    //   8 KiB
    unsigned short* Whh0b = (unsigned short*)(ws + (135u << 20) + 8192);
    unsigned short* Wih1b = (unsigned short*)(ws + (135u << 20) + 8192 + 24576);

    gt_kernel   <<<dim3(16, 16), 256, 0, stream>>>(G, GTb);
    gh1ct_kernel<<<M_, 192, 0, stream>>>(H_init, Whh1, bhh1, gh1cT);
    wn_kernel   <<<RD_, 128, 0, stream>>>(V, gvec, Wnb);
    castw_kernel<<<48, 256, 0, stream>>>(Whh0, Wih1, Whh0b, Wih1b);
    inith_kernel<<<1024, 256, 0, stream>>>(H_init, Hb);

    for (int c = 0; c < W_ / CH_; ++c) {
        gru_chunk_kernel<<<512, 512, 0, stream>>>(x_input, Wih0, bih0, bhh0, Whh0b,
                                                  Wih1b, bih1, gh1cT, H_init, Hb,
                                                  XPT_c, c * CH_);
        gemmhead_kernel<<<dim3(4096), 256, 0, stream>>>(GTb, XPT_c, Wnb, b_lin,
                                                        W_fr, b_fr, out, c * CH_);
    }
}

// Round 14
// 584.379 us; speedup vs baseline: 1.0191x; 1.0191x over previous
//
#include <hip/hip_runtime.h>
#include <math.h>

#define B_  32
#define W_  32
#define M_  1024
#define HD_ 64
#define RD_ 32
#define D_  128
#define CH_ 16           // time-steps per chunk (2 chunks)
#define NKT 16           // K-tiles (K=1024, BK=64) in gemm

typedef short bf16x8 __attribute__((ext_vector_type(8)));
typedef float f32x4  __attribute__((ext_vector_type(4)));

#define AS1 __attribute__((address_space(1)))
#define AS3 __attribute__((address_space(3)))

__device__ __forceinline__ void gload16(const void* g, void* l) {
    __builtin_amdgcn_global_load_lds((const AS1 void*)g, (AS3 void*)l, 16, 0, 0);
}

// LDS-only barrier: lgkmcnt(0)+s_barrier. Unlike __syncthreads (which emits
// s_waitcnt vmcnt(0) lgkmcnt(0)), this does NOT drain global stores/loads --
// removes a ~400-900cy HBM round-trip from every gru step (stores have no
// intra-kernel readers; LDS visibility fully covered by lgkmcnt(0)).
__device__ __forceinline__ void bar_lds() {
    asm volatile("s_waitcnt lgkmcnt(0)" ::: "memory");
    __builtin_amdgcn_s_barrier();
    asm volatile("" ::: "memory");
}

__device__ __forceinline__ unsigned short f2b(float f) {
    unsigned int u = __float_as_uint(f);
    u += 0x7fffu + ((u >> 16) & 1u);
    return (unsigned short)(u >> 16);
}
__device__ __forceinline__ float b2f(unsigned short h) {
    return __uint_as_float(((unsigned int)h) << 16);
}
__device__ __forceinline__ float sigf(float x) { return 1.0f / (1.0f + __expf(-x)); }
__device__ __forceinline__ float tanhf_(float x) { return 2.0f / (1.0f + __expf(-2.0f * x)) - 1.0f; }

// ---------------- setup kernels ----------------

__global__ __launch_bounds__(256) void gt_kernel(const float* __restrict__ G,
                                                 unsigned short* __restrict__ GTb) {
    __shared__ float T[64][65];
    int i0 = blockIdx.x * 64, j0 = blockIdx.y * 64;
    int tid = threadIdx.x;
    int r = tid >> 4, c4 = (tid & 15) * 4;
    #pragma unroll
    for (int q = 0; q < 4; ++q) {
        float4 v = *(const float4*)&G[(i0 + r + q * 16) * M_ + j0 + c4];
        T[r + q * 16][c4] = v.x; T[r + q * 16][c4 + 1] = v.y;
        T[r + q * 16][c4 + 2] = v.z; T[r + q * 16][c4 + 3] = v.w;
    }
    __syncthreads();
    #pragma unroll
    for (int q = 0; q < 4; ++q) {
        int jr = r + q * 16;
        ushort4 o;
        o.x = f2b(T[c4][jr]); o.y = f2b(T[c4 + 1][jr]);
        o.z = f2b(T[c4 + 2][jr]); o.w = f2b(T[c4 + 3][jr]);
        *(ushort4*)&GTb[(j0 + jr) * M_ + i0 + c4] = o;
    }
}

__global__ __launch_bounds__(192) void gh1ct_kernel(const float* __restrict__ H_init,
                                                    const float* __restrict__ Whh1,
                                                    const float* __restrict__ bhh1,
                                                    float* __restrict__ gh1cT) {
    int m = blockIdx.x, k = threadIdx.x;
    __shared__ float h01[HD_];
    if (k < HD_) h01[k] = H_init[(M_ + m) * HD_ + k];
    __syncthreads();
    float d = 0.f;
    #pragma unroll
    for (int hd = 0; hd < HD_; ++hd) d = fmaf(h01[hd], Whh1[k * HD_ + hd], d);
    gh1cT[k * M_ + m] = d + bhh1[k];
}

__global__ __launch_bounds__(128) void wn_kernel(const float* __restrict__ V,
                                                 const float* __restrict__ g,
                                                 unsigned short* __restrict__ Wnb) {
    int r = blockIdx.x, d = threadIdx.x;
    float v = V[r * D_ + d];
    float s = v * v;
    #pragma unroll
    for (int off = 32; off > 0; off >>= 1) s += __shfl_down(s, off);
    __shared__ float ws[2];
    if ((threadIdx.x & 63) == 0) ws[threadIdx.x >> 6] = s;
    __syncthreads();
    float norm = sqrtf(ws[0] + ws[1]);
    Wnb[r * D_ + d] = f2b(g[r] * v / norm);
}

__global__ __launch_bounds__(256) void castw_kernel(const float* __restrict__ Whh0,
                                                    const float* __restrict__ Wih1,
                                                    unsigned short* __restrict__ Whh0b,
                                                    unsigned short* __restrict__ Wih1b) {
    int i = blockIdx.x * 256 + threadIdx.x;  // < 12288
    Whh0b[i] = f2b(Whh0[i]);
    Wih1b[i] = f2b(Wih1[i]);
}

__global__ __launch_bounds__(256) void inith_kernel(const float* __restrict__ H_init,
                                                    unsigned short* __restrict__ Hb) {
    int e8 = blockIdx.x * 256 + threadIdx.x;   // 262144 total
    int base = e8 * 8;
    int src = base & (M_ * HD_ - 1);
    float4 v0 = *(const float4*)&H_init[src];
    float4 v1 = *(const float4*)&H_init[src + 4];
    uint4 u;
    u.x = (unsigned int)f2b(v0.x) | ((unsigned int)f2b(v0.y) << 16);
    u.y = (unsigned int)f2b(v0.z) | ((unsigned int)f2b(v0.w) << 16);
    u.z = (unsigned int)f2b(v1.x) | ((unsigned int)f2b(v1.y) << 16);
    u.w = (unsigned int)f2b(v1.z) | ((unsigned int)f2b(v1.w) << 16);
    *(uint4*)&Hb[base] = u;
}

// ---------------- per-chunk: fused GRU0+GRU1, 16 time-steps -----------------
// R7/R12-validated structure; the 3 steady-state __syncthreads replaced by
// bar_lds() (lgkm-only). Initial barrier keeps the full vmcnt drain (guards
// global_load_lds weight staging).
__global__ __launch_bounds__(512, 4) void gru_chunk_kernel(
    const float* __restrict__ x_input, const float* __restrict__ Wih0,
    const float* __restrict__ bih0, const float* __restrict__ bhh0,
    const unsigned short* __restrict__ Whh0b, const unsigned short* __restrict__ Wih1b,
    const float* __restrict__ bih1, const float* __restrict__ gh1cT,
    const float* __restrict__ H_init, unsigned short* __restrict__ Hb,
    unsigned short* __restrict__ XPT_c, int t0)
{
    __shared__ unsigned short Whh0s[192 * 64];   // 24 KB, swizzled rows of 8x16B
    __shared__ unsigned short Wih1s[192 * 64];   // 24 KB
    __shared__ unsigned short hn0s[64 * 64];     // 8 KB, swizzled
    __shared__ unsigned short hn1s[64 * 64];     // 8 KB, swizzled (current state)
    const int tid = threadIdx.x, w = tid >> 6, l = tid & 63;
    const int li = l & 15, lh = l >> 4;
    const int pg = w >> 1, hf = w & 1;           // pair-group / j-half
    const int b = blockIdx.x >> 4, mt = blockIdx.x & 15;
    const int m0 = mt * 64;
    const int p0b = b * M_ + m0;
    const int ms = m0 + pg * 16;

    for (int i = tid; i < 1536; i += 512) {
        int row = i >> 3, pos = i & 7, sc = pos ^ (row & 7);
        gload16(&Whh0b[row * 64 + sc * 8], (char*)Whh0s + (i & ~63) * 16);
        gload16(&Wih1b[row * 64 + sc * 8], (char*)Wih1s + (i & ~63) * 16);
    }
    {
        int p = tid >> 3, cc = tid & 7;
        uint4 v = *(const uint4*)&Hb[(p0b + p) * HD_ + cc * 8];
        *(uint4*)((char*)hn1s + p * 128 + ((cc ^ (p & 7)) << 4)) = v;
    }

    float wi_[3][2], bi0_[3][2], bh0_[3][2], bi1_[3][2];
    float vrA[2][4], vzA[2][4], vnA[2][4], h01A[2][4];
    #pragma unroll
    for (int fi = 0; fi < 2; ++fi) {
        int ko = hf * 32 + fi * 16 + li;
        #pragma unroll
        for (int g3 = 0; g3 < 3; ++g3) {
            wi_[g3][fi]  = Wih0[g3 * 64 + ko];
            bi0_[g3][fi] = bih0[g3 * 64 + ko];
            bh0_[g3][fi] = bhh0[g3 * 64 + ko];
            bi1_[g3][fi] = bih1[g3 * 64 + ko];
        }
        float4 vr = *(const float4*)&gh1cT[(ko) * M_ + ms + lh * 4];
        float4 vz = *(const float4*)&gh1cT[(64 + ko) * M_ + ms + lh * 4];
        float4 vn = *(const float4*)&gh1cT[(128 + ko) * M_ + ms + lh * 4];
        vrA[fi][0] = vr.x; vrA[fi][1] = vr.y; vrA[fi][2] = vr.z; vrA[fi][3] = vr.w;
        vzA[fi][0] = vz.x; vzA[fi][1] = vz.y; vzA[fi][2] = vz.z; vzA[fi][3] = vz.w;
        vnA[fi][0] = vn.x; vnA[fi][1] = vn.y; vnA[fi][2] = vn.z; vnA[fi][3] = vn.w;
        #pragma unroll
        for (int reg = 0; reg < 4; ++reg)
            h01A[fi][reg] = H_init[M_ * HD_ + (ms + lh * 4 + reg) * HD_ + ko];
    }

    // initial barrier: FULL drain (gload_lds weights + hn1s ds_writes)
    asm volatile("s_waitcnt vmcnt(0) lgkmcnt(0)" ::: "memory");
    __builtin_amdgcn_s_barrier();
    asm volatile("" ::: "memory");

    float hst[2][4];
    #pragma unroll
    for (int fi = 0; fi < 2; ++fi) {
        int ko = hf * 32 + fi * 16 + li;
        #pragma unroll
        for (int reg = 0; reg < 4; ++reg) {
            int ml = pg * 16 + lh * 4 + reg;
            hst[fi][reg] = b2f(*(const unsigned short*)((char*)hn1s + ml * 128 +
                               ((((ko >> 3) ^ (ml & 7))) << 4) + (ko & 7) * 2));
        }
    }

    for (int ts = 0; ts < CH_; ++ts) {
        int t = t0 + ts;
        float4 xv = *(const float4*)&x_input[(b * W_ + t) * M_ + ms + lh * 4];
        float x4[4] = {xv.x, xv.y, xv.z, xv.w};
        const int rl = pg * 16 + li;

        // ---- GRU0 matvec (half): gh0[j in hf-range] = h(16x64) @ Whh0^T ----
        bf16x8 a0 = *(const bf16x8*)((char*)hn1s + rl * 128 + ((lh ^ (rl & 7)) << 4));
        bf16x8 a1 = *(const bf16x8*)((char*)hn1s + rl * 128 + (((4 + lh) ^ (rl & 7)) << 4));
        f32x4 acc[6];
        #pragma unroll
        for (int q = 0; q < 6; ++q) acc[q] = (f32x4){0.f, 0.f, 0.f, 0.f};
        #pragma unroll
        for (int g3 = 0; g3 < 3; ++g3)
            #pragma unroll
            for (int fi = 0; fi < 2; ++fi) {
                int row = (g3 * 4 + hf * 2 + fi) * 16 + li;
                bf16x8 b0 = *(const bf16x8*)((char*)Whh0s + row * 128 + ((lh ^ (row & 7)) << 4));
                bf16x8 b1 = *(const bf16x8*)((char*)Whh0s + row * 128 + (((4 + lh) ^ (row & 7)) << 4));
                acc[g3 * 2 + fi] = __builtin_amdgcn_mfma_f32_16x16x32_bf16(a0, b0, acc[g3 * 2 + fi], 0, 0, 0);
                acc[g3 * 2 + fi] = __builtin_amdgcn_mfma_f32_16x16x32_bf16(a1, b1, acc[g3 * 2 + fi], 0, 0, 0);
            }
        #pragma unroll
        for (int fi = 0; fi < 2; ++fi) {
            int j = hf * 32 + fi * 16 + li;
            #pragma unroll
            for (int reg = 0; reg < 4; ++reg) {
                int ml = pg * 16 + lh * 4 + reg;
                float x = x4[reg];
                float r = sigf(x * wi_[0][fi] + bi0_[0][fi] + acc[fi][reg]     + bh0_[0][fi]);
                float z = sigf(x * wi_[1][fi] + bi0_[1][fi] + acc[2 + fi][reg] + bh0_[1][fi]);
                float n = tanhf_(x * wi_[2][fi] + bi0_[2][fi] + r * (acc[4 + fi][reg] + bh0_[2][fi]));
                float h0v = (1.f - z) * n + z * hst[fi][reg];
                *(unsigned short*)((char*)hn0s + ml * 128 +
                    ((((j >> 3) ^ (ml & 7))) << 4) + (j & 7) * 2) = f2b(h0v);
            }
        }
        bar_lds();   // B1: both halves of hn0s ready (LDS-only)

        // ---- GRU1 matvec (half): gi1[j in hf-range] = hn0(16x64) @ Wih1^T ----
        a0 = *(const bf16x8*)((char*)hn0s + rl * 128 + ((lh ^ (rl & 7)) << 4));
        a1 = *(const bf16x8*)((char*)hn0s + rl * 128 + (((4 + lh) ^ (rl & 7)) << 4));
        #pragma unroll
        for (int q = 0; q < 6; ++q) acc[q] = (f32x4){0.f, 0.f, 0.f, 0.f};
        #pragma unroll
        for (int g3 = 0; g3 < 3; ++g3)
            #pragma unroll
            for (int fi = 0; fi < 2; ++fi) {
                int row = (g3 * 4 + hf * 2 + fi) * 16 + li;
                bf16x8 b0 = *(const bf16x8*)((char*)Wih1s + row * 128 + ((lh ^ (row & 7)) << 4));
                bf16x8 b1 = *(const bf16x8*)((char*)Wih1s + row * 128 + (((4 + lh) ^ (row & 7)) << 4));
                acc[g3 * 2 + fi] = __builtin_amdgcn_mfma_f32_16x16x32_bf16(a0, b0, acc[g3 * 2 + fi], 0, 0, 0);
                acc[g3 * 2 + fi] = __builtin_amdgcn_mfma_f32_16x16x32_bf16(a1, b1, acc[g3 * 2 + fi], 0, 0, 0);
            }
        #pragma unroll
        for (int fi = 0; fi < 2; ++fi) {
            int ko = hf * 32 + fi * 16 + li;
            #pragma unroll
            for (int reg = 0; reg < 4; ++reg) {
                int ml = pg * 16 + lh * 4 + reg;
                float r = sigf(acc[fi][reg]     + bi1_[0][fi] + vrA[fi][reg]);
                float z = sigf(acc[2 + fi][reg] + bi1_[1][fi] + vzA[fi][reg]);
                float n = tanhf_(acc[4 + fi][reg] + bi1_[2][fi] + r * vnA[fi][reg]);
                float h1v = (1.f - z) * n + z * h01A[fi][reg];
                hst[fi][reg] = h1v;          // f32 recurrent carry
                *(unsigned short*)((char*)hn1s + ml * 128 +
                    ((((ko >> 3) ^ (ml & 7))) << 4) + (ko & 7) * 2) = f2b(h1v);
            }
        }
        bar_lds();   // B2: hn1s (new state) ready (LDS-only)

        // ---- XPT write (transposed bf16 rows [c][m]); 512 thr pack 128 d ----
        {
            unsigned short* XPT = XPT_c + (size_t)ts * (D_ * B_ * M_);
            int d = tid >> 2, mh = (tid & 3) * 16;
            const char* src = (d < 64) ? (const char*)hn0s : (const char*)hn1s;
            int dd = d & 63;
            unsigned int pk[8];
            #pragma unroll
            for (int mm = 0; mm < 16; mm += 2) {
                int ma = mh + mm, mb = mh + mm + 1;
                unsigned int ua = *(const unsigned short*)(src + ma * 128 + (((dd >> 3) ^ (ma & 7)) << 4) + (dd & 7) * 2);
                unsigned int ub = *(const unsigned short*)(src + mb * 128 + (((dd >> 3) ^ (mb & 7)) << 4) + (dd & 7) * 2);
                pk[mm >> 1] = ua | (ub << 16);
            }
            uint4 o0 = {pk[0], pk[1], pk[2], pk[3]};
            uint4 o1 = {pk[4], pk[5], pk[6], pk[7]};
            *(uint4*)&XPT[(b * D_ + d) * M_ + m0 + mh]     = o0;
            *(uint4*)&XPT[(b * D_ + d) * M_ + m0 + mh + 8] = o1;
        }
        bar_lds();   // B3: pack LDS-reads retired; stores NOT drained (no reader here)
    }

    // state writeback
    {
        int p = tid >> 3, cc = tid & 7;
        uint4 v = *(const uint4*)((char*)hn1s + p * 128 + ((cc ^ (p & 7)) << 4));
        *(uint4*)&Hb[(p0b + p) * HD_ + cc * 8] = v;
    }
}

// ---------------- per-chunk: 128x128 BK=64 dbuf graph GEMM + fused head -----
// R12-validated kernel, byte-identical. 512 thr / 8 waves (2Mx4N), grid 4096.
__global__ __launch_bounds__(512, 4) void gemmhead_kernel(
    const unsigned short* __restrict__ GTb, const unsigned short* __restrict__ XPT_c,
    const unsigned short* __restrict__ Wnb, const float* __restrict__ b_lin,
    const float* __restrict__ W_fr, const float* __restrict__ b_fr,
    float* __restrict__ out, int t0)
{
    __shared__ __align__(16) char lds[65536];  // 2 x (A 16K + B 16K); reused as XGs 32K
    const int tid = threadIdx.x, w = tid >> 6, l = tid & 63;
    const int li = l & 15, lh = l >> 4;      // lh 0..3
    const int wm = w >> 2, wn = w & 3;       // 2 x 4 wave grid
    const int bid = blockIdx.x;
    const int ntile = (bid & 7) + ((bid >> 6) << 3);   // 0..511 (ts*32+b)
    const int j0 = ((bid >> 3) & 7) * 128;             // 8 j-tiles (same-XCD sharers)
    const unsigned short* Asrc = GTb + (size_t)j0 * M_;
    const unsigned short* Bsrc = XPT_c + (size_t)ntile * 128 * M_;

    f32x4 acc[4][2];
    #pragma unroll
    for (int mi = 0; mi < 4; ++mi)
        #pragma unroll
        for (int ni = 0; ni < 2; ++ni) acc[mi][ni] = (f32x4){0.f, 0.f, 0.f, 0.f};

    #define STAGE(kt, c) { \
        _Pragma("unroll") \
        for (int q = 0; q < 2; ++q) { \
            int i = q * 512 + tid; \
            int row = i >> 3, pos = i & 7, sc = pos ^ (row & 7); \
            gload16(&Asrc[row * M_ + (kt) * 64 + sc * 8], lds + (c) * 32768 + (i & ~63) * 16); \
            gload16(&Bsrc[row * M_ + (kt) * 64 + sc * 8], lds + (c) * 32768 + 16384 + (i & ~63) * 16); \
        } }

    STAGE(0, 0);

    for (int kt = 0; kt < NKT; ++kt) {
        if (kt + 1 < NKT) { STAGE(kt + 1, (kt + 1) & 1);
                            asm volatile("s_waitcnt vmcnt(4)" ::: "memory"); }
        else              { asm volatile("s_waitcnt vmcnt(0)" ::: "memory"); }
        __builtin_amdgcn_s_barrier();
        asm volatile("" ::: "memory");
        const char* Abuf = lds + (kt & 1) * 32768;
        const char* Bbuf = Abuf + 16384;
        bf16x8 af[4][2], bfv[2][2];
        #pragma unroll
        for (int mi = 0; mi < 4; ++mi) {
            int row = wm * 64 + mi * 16 + li;
            #pragma unroll
            for (int kk = 0; kk < 2; ++kk)
                af[mi][kk] = *(const bf16x8*)(Abuf + row * 128 + (((kk * 4 + lh) ^ (row & 7)) << 4));
        }
        #pragma unroll
        for (int ni = 0; ni < 2; ++ni) {
            int row = wn * 32 + ni * 16 + li;
            #pragma unroll
            for (int kk = 0; kk < 2; ++kk)
                bfv[ni][kk] = *(const bf16x8*)(Bbuf + row * 128 + (((kk * 4 + lh) ^ (row & 7)) << 4));
        }
        __builtin_amdgcn_s_setprio(1);
        #pragma unroll
        for (int kk = 0; kk < 2; ++kk)
            #pragma unroll
            for (int mi = 0; mi < 4; ++mi)
                #pragma unroll
                for (int ni = 0; ni < 2; ++ni)
                    acc[mi][ni] = __builtin_amdgcn_mfma_f32_16x16x32_bf16(af[mi][kk], bfv[ni][kk], acc[mi][ni], 0, 0, 0);
        __builtin_amdgcn_s_setprio(0);
        asm volatile("s_waitcnt lgkmcnt(0)" ::: "memory");  // reads done before bar2
        __builtin_amdgcn_s_barrier();
        asm volatile("" ::: "memory");
    }

    __syncthreads();   // full drain; staging LDS becomes XGs

    // relu -> bf16 -> XGs[128][128] (row 256 B = 16 chunks, XOR low3 w/ row&7)
    #pragma unroll
    for (int mi = 0; mi < 4; ++mi)
        #pragma unroll
        for (int ni = 0; ni < 2; ++ni)
            #pragma unroll
            for (int reg = 0; reg < 4; ++reg) {
                int jl = wm * 64 + mi * 16 + lh * 4 + reg;
                int cl = wn * 32 + ni * 16 + li;
                float v = fmaxf(acc[mi][ni][reg], 0.f);
                int byte = jl * 256 + ((((cl >> 3) ^ (jl & 7))) << 4) + (cl & 7) * 2;
                *(unsigned short*)(lds + byte) = f2b(v);
            }
    __syncthreads();

    // head: wave w does rows w*16..w*16+15 ; P[j][r] = XG[j][:] . Wn[r][:]
    const int b = ntile & 31, t = t0 + (ntile >> 5);
    float bl0 = b_lin[li], bl1 = b_lin[16 + li];
    {
        int row = w * 16 + li;
        f32x4 P0 = (f32x4){0.f, 0.f, 0.f, 0.f};
        f32x4 P1 = (f32x4){0.f, 0.f, 0.f, 0.f};
        #pragma unroll
        for (int ks = 0; ks < 4; ++ks) {
            int cp = (ks * 4 + lh) ^ (row & 7);
            bf16x8 xa = *(const bf16x8*)(lds + row * 256 + cp * 16);
            bf16x8 wb0 = *(const bf16x8*)&Wnb[(li) * D_ + ks * 32 + lh * 8];
            bf16x8 wb1 = *(const bf16x8*)&Wnb[(16 + li) * D_ + ks * 32 + lh * 8];
            P0 = __builtin_amdgcn_mfma_f32_16x16x32_bf16(xa, wb0, P0, 0, 0, 0);
            P1 = __builtin_amdgcn_mfma_f32_16x16x32_bf16(xa, wb1, P1, 0, 0, 0);
        }
        float s[4];
        #pragma unroll
        for (int reg = 0; reg < 4; ++reg) {
            int j = j0 + w * 16 + lh * 4 + reg;
            float y0 = sigf(P0[reg] + bl0);
            float y1 = sigf(P1[reg] + bl1);
            s[reg] = y0 * W_fr[j * RD_ + li] + y1 * W_fr[j * RD_ + 16 + li];
        }
        #pragma unroll
        for (int off = 1; off < 16; off <<= 1) {
            #pragma unroll
            for (int reg = 0; reg < 4; ++reg) s[reg] += __shfl_xor(s[reg], off);
        }
        if (li == 0) {
            int jb = j0 + w * 16 + lh * 4;
            float4 o = {s[0] + b_fr[jb], s[1] + b_fr[jb + 1],
                        s[2] + b_fr[jb + 2], s[3] + b_fr[jb + 3]};
            *(float4*)&out[(b * W_ + t) * M_ + jb] = o;
        }
    }
}

// ---------------- launcher ----------------

extern "C" void kernel_launch(void* const* d_in, const int* in_sizes, int n_in,
                              void* d_out, int out_size, void* d_ws, size_t ws_size,
                              hipStream_t stream) {
    const float* x_input = (const float*)d_in[0];
    const float* G       = (const float*)d_in[1];
    const float* H_init  = (const float*)d_in[2];
    const float* Wih0    = (const float*)d_in[3];
    const float* Whh0    = (const float*)d_in[4];
    const float* bih0    = (const float*)d_in[5];
    const float* bhh0    = (const float*)d_in[6];
    const float* Wih1    = (const float*)d_in[7];
    const float* Whh1    = (const float*)d_in[8];
    const float* bih1    = (const float*)d_in[9];
    const float* bhh1    = (const float*)d_in[10];
    const float* V       = (const float*)d_in[11];
    const float* gvec    = (const float*)d_in[12];
    const float* b_lin   = (const float*)d_in[13];
    const float* W_fr    = (const float*)d_in[14];
    const float* b_fr    = (const float*)d_in[15];
    float* out = (float*)d_out;

    // ws layout (bytes), total ~135.1 MiB of the 256 MiB workspace
    char* ws = (char*)d_ws;
    unsigned short* GTb   = (unsigned short*)(ws);                   //   2 MiB
    unsigned short* XPT_c = (unsigned short*)(ws + (2u   << 20));    // 128 MiB (16 steps x 8 MiB)
    unsigned short* Hb    = (unsigned short*)(ws + (130u << 20));    //   4 MiB
    float*          gh1cT = (float*)(ws + (134u << 20));             // 768 KiB
    unsigned short* Wnb   = (unsigned short*)(ws + (135u << 20));    //   8 KiB
    unsigned short* Whh0b = (unsigned short*)(ws + (135u << 20) + 8192);
    unsigned short* Wih1b = (unsigned short*)(ws + (135u << 20) + 8192 + 24576);

    gt_kernel   <<<dim3(16, 16), 256, 0, stream>>>(G, GTb);
    gh1ct_kernel<<<M_, 192, 0, stream>>>(H_init, Whh1, bhh1, gh1cT);
    wn_kernel   <<<RD_, 128, 0, stream>>>(V, gvec, Wnb);
    castw_kernel<<<48, 256, 0, stream>>>(Whh0, Wih1, Whh0b, Wih1b);
    inith_kernel<<<1024, 256, 0, stream>>>(H_init, Hb);

    for (int c = 0; c < W_ / CH_; ++c) {
        gru_chunk_kernel<<<512, 512, 0, stream>>>(x_input, Wih0, bih0, bhh0, Whh0b,
                                                  Wih1b, bih1, gh1cT, H_init, Hb,
                                                  XPT_c, c * CH_);
        gemmhead_kernel<<<dim3(4096), 512, 0, stream>>>(GTb, XPT_c, Wnb, b_lin,
                                                        W_fr, b_fr, out, c * CH_);
    }
}